// Round 7
// baseline (8360.259 us; speedup 1.0000x reference)
//
#include <hip/hip_runtime.h>
#include <hip/hip_bf16.h>

#define VOCAB 50000
#define DD 128
#define TT 512
#define BB 512
#define HH 100
#define NCLS 4
#define NT 25            // 16-wide permuted col tiles covering 4H=400 exactly
#define ROWS 4           // real batch rows per block
#define NBLK (BB/ROWS)   // 128 blocks
#define NTHREADS 512     // 8 waves
#define ZS 400           // z_lds row stride (f32, float4-aligned)

typedef short s16x8 __attribute__((ext_vector_type(8)));
typedef float f32x4 __attribute__((ext_vector_type(4)));

static __device__ __forceinline__ unsigned short f2b(float x) {
    __hip_bfloat16 h = __float2bfloat16(x);
    return __builtin_bit_cast(unsigned short, h);
}
static __device__ __forceinline__ float sigm(float x)  { return __fdividef(1.0f, 1.0f + __expf(-x)); }
static __device__ __forceinline__ float tanhx(float x) { return 1.0f - __fdividef(2.0f, 1.0f + __expf(2.0f * x)); }

// raw barrier: waits LDS ops only; global loads (vmcnt) stay in flight
#define BARRIER() asm volatile("s_waitcnt lgkmcnt(0)\n\ts_barrier" ::: "memory")

// ---------------- prep: cast embedding table f32 -> bf16 ----------------
__global__ void cast_emb_k(const float* __restrict__ emb, unsigned short* __restrict__ out, int n4) {
    int i = blockIdx.x * blockDim.x + threadIdx.x;
    if (i < n4) {
        float4 v = reinterpret_cast<const float4*>(emb)[i];
        ushort4 o = make_ushort4(f2b(v.x), f2b(v.y), f2b(v.z), f2b(v.w));
        reinterpret_cast<ushort4*>(out)[i] = o;
    }
}

// ---------------- prep: bake kernel & rec_kernel into per-lane MFMA B-fragments ----------------
// PERMUTED columns: dest col c' = j*4 + gate  <->  orig col = (c'&3)*100 + (c'>>2)
__global__ void build_frags_k(const float* __restrict__ kern, const float* __restrict__ rec,
                              unsigned short* __restrict__ ikf, unsigned short* __restrict__ recf) {
    int tid = blockIdx.x * blockDim.x + threadIdx.x;
    if (tid >= 2 * NT * 4 * 64) return;
    int tab  = tid / (NT * 4 * 64);
    int rem  = tid % (NT * 4 * 64);
    int lane = rem & 63;
    int fs   = rem >> 6;
    int ks   = fs & 3, nt = fs >> 2;
    int cp    = nt * 16 + (lane & 15);           // permuted col
    int oc    = (cp & 3) * 100 + (cp >> 2);      // original col
    int kbase = ks * 32 + (lane >> 4) * 8;
    unsigned short* dst = (tab ? recf : ikf) + rem * 8;
#pragma unroll
    for (int j = 0; j < 8; ++j) {
        int k = kbase + j;
        float v;
        if (tab == 0) v = kern[k * 400 + oc];
        else          v = (k < HH) ? rec[k * 400 + oc] : 0.0f;
        dst[j] = f2b(v);
    }
}

// ---------------- REAL kernel: R4 structure verbatim (known ~670 us anchor) ----------------
__global__ __launch_bounds__(NTHREADS, 2)
void lstm_fused2_k(const int* __restrict__ tokens,
                   const float* __restrict__ bias,
                   const float* __restrict__ dw,
                   const float* __restrict__ db,
                   const unsigned short* __restrict__ emb_bf,
                   const unsigned short* __restrict__ ikf_tab,
                   const unsigned short* __restrict__ recf_tab,
                   float* __restrict__ out)
{
    __shared__ __align__(16) unsigned short h_lds[2][16 * DD];
    __shared__ float z_lds[ROWS][ZS];
    __shared__ float hf_lds[ROWS * HH];
    __shared__ float dw_lds[HH * NCLS];
    __shared__ int   tok_lds[ROWS][TT];

    const int tid = threadIdx.x, lane = tid & 63, w = tid >> 6;
    const int lo = lane & 15, hi = lane >> 4;
    const int b0 = blockIdx.x * ROWS;
    const int nt0 = (w * NT) >> 3;
    const int cnt = (((w + 1) * NT) >> 3) - nt0;

    s16x8 ikf[4][4], rcf[4][4];
    float bv[4];
#pragma unroll
    for (int i = 0; i < 4; ++i) {
        if (i < cnt) {
            int cp = (nt0 + i) * 16 + lo;
            bv[i] = bias[(cp & 3) * 100 + (cp >> 2)];
#pragma unroll
            for (int ks = 0; ks < 4; ++ks) {
                ikf[i][ks] = *reinterpret_cast<const s16x8*>(ikf_tab  + (((nt0 + i) * 4 + ks) * 64 + lane) * 8);
                rcf[i][ks] = *reinterpret_cast<const s16x8*>(recf_tab + (((nt0 + i) * 4 + ks) * 64 + lane) * 8);
            }
        } else {
            bv[i] = 0.0f;
#pragma unroll
            for (int ks = 0; ks < 4; ++ks) { ikf[i][ks] = (s16x8)0; rcf[i][ks] = (s16x8)0; }
        }
    }
#pragma unroll
    for (int i = 0; i < 4; ++i) {
        asm volatile("" : "+v"(bv[i]));
#pragma unroll
        for (int ks = 0; ks < 4; ++ks) {
            asm volatile("" : "+v"(ikf[i][ks]));
            asm volatile("" : "+v"(rcf[i][ks]));
        }
    }

    for (int idx = tid; idx < 16 * DD; idx += NTHREADS)
        reinterpret_cast<unsigned int*>(&h_lds[0][0])[idx] = 0u;
    for (int idx = tid; idx < ROWS * TT; idx += NTHREADS)
        tok_lds[idx >> 9][idx & (TT - 1)] = tokens[(b0 + (idx >> 9)) * TT + (idx & (TT - 1))];
    if (tid < HH * NCLS) dw_lds[tid] = dw[tid];

    const int  grow = hi;
    const int  gjl  = lo;
    const bool g_on = gjl < 4 * cnt;
    float cst = 0.0f;

    const int xrow = lo & 3;
    int hof[4];
#pragma unroll
    for (int ks = 0; ks < 4; ++ks)
        hof[ks] = (lo * 256 + ks * 64 + hi * 16) ^ ((lo & 7) << 4);

    s16x8 xfA[4], xfB[4];
    {
        int t0 = tokens[(b0 + xrow) * TT + 0];
        int t1 = tokens[(b0 + xrow) * TT + 1];
#pragma unroll
        for (int ks = 0; ks < 4; ++ks) {
            xfA[ks] = *reinterpret_cast<const s16x8*>(emb_bf + (long)t0 * DD + ks * 32 + hi * 8);
            xfB[ks] = *reinterpret_cast<const s16x8*>(emb_bf + (long)t1 * DD + ks * 32 + hi * 8);
        }
    }
    __syncthreads();

    auto step = [&](int t, s16x8 (&xf)[4],
                    const unsigned short* hrd, unsigned short* hwr) {
        s16x8 hA[4];
#pragma unroll
        for (int ks = 0; ks < 4; ++ks)
            hA[ks] = *reinterpret_cast<const s16x8*>(reinterpret_cast<const char*>(hrd) + hof[ks]);

        f32x4 acc[4];
#pragma unroll
        for (int i = 0; i < 4; ++i) { acc[i][0] = bv[i]; acc[i][1] = bv[i]; acc[i][2] = bv[i]; acc[i][3] = bv[i]; }

#pragma unroll
        for (int ks = 0; ks < 4; ++ks)
#pragma unroll
            for (int i = 0; i < 4; ++i)
                if (i < cnt) acc[i] = __builtin_amdgcn_mfma_f32_16x16x32_bf16(xf[ks], ikf[i][ks], acc[i], 0, 0, 0);

        {
            int t2 = (t + 2 < TT) ? t + 2 : TT - 1;
            int tk = tok_lds[xrow][t2];
            const unsigned short* ep = emb_bf + (long)tk * DD;
#pragma unroll
            for (int ks = 0; ks < 4; ++ks)
                xf[ks] = *reinterpret_cast<const s16x8*>(ep + ks * 32 + hi * 8);
        }

#pragma unroll
        for (int ks = 0; ks < 4; ++ks)
#pragma unroll
            for (int i = 0; i < 4; ++i)
                if (i < cnt) acc[i] = __builtin_amdgcn_mfma_f32_16x16x32_bf16(hA[ks], rcf[i][ks], acc[i], 0, 0, 0);

        if (hi == 0) {
#pragma unroll
            for (int i = 0; i < 4; ++i) if (i < cnt)
#pragma unroll
                for (int r = 0; r < 4; ++r)
                    z_lds[r][(nt0 + i) * 16 + lo] = acc[i][r];
        }

        if (g_on) {
            float4 z4 = *reinterpret_cast<const float4*>(&z_lds[grow][nt0 * 16 + gjl * 4]);
            float ig = sigm(z4.x), fg = sigm(z4.y), gg = tanhx(z4.z), og = sigm(z4.w);
            cst = fg * cst + ig * gg;
            float hh = og * tanhx(cst);
            int j = nt0 * 4 + gjl;
            *reinterpret_cast<unsigned short*>(reinterpret_cast<char*>(hwr) +
                ((grow * 256 + j * 2) ^ (grow << 4))) = f2b(hh);
            if (t == TT - 1) hf_lds[grow * HH + j] = hh;
        }
        BARRIER();
    };

    for (int t = 0; t < TT; t += 2) {
        step(t,     xfA, h_lds[1], h_lds[0]);
        step(t + 1, xfB, h_lds[0], h_lds[1]);
    }

    if (tid < ROWS * NCLS) {
        int r = tid >> 2, c = tid & 3;
        float s = db[c];
#pragma unroll 4
        for (int k = 0; k < HH; ++k)
            s += hf_lds[r * HH + k] * dw_lds[k * NCLS + c];
        float mx = s;
        mx = fmaxf(mx, __shfl_xor(mx, 1));
        mx = fmaxf(mx, __shfl_xor(mx, 2));
        float e = __expf(s - mx);
        float den = e;
        den += __shfl_xor(den, 1);
        den += __shfl_xor(den, 2);
        out[(b0 + r) * NCLS + c] = e / den;
    }
}

// ---------------- ABLATION body (device), instantiated by NAMED wrappers ----------------
// ABL=0 full | ABL=1 no barrier | ABL=3 no hA ds_read | ABL=5 no x-prefetch | ABL=6 MFMA-only floor
template<int ABL, int TTV, int REP>
__device__ __forceinline__ void lstm_abl_body(const int* __restrict__ tokens,
                                              const float* __restrict__ bias,
                                              const unsigned short* __restrict__ emb_bf,
                                              const unsigned short* __restrict__ ikf_tab,
                                              const unsigned short* __restrict__ recf_tab,
                                              float* __restrict__ vout)
{
    __shared__ __align__(16) unsigned short h_lds[2][16 * DD];
    __shared__ float z_lds[ROWS][ZS];
    __shared__ float hf_lds[ROWS * HH];
    __shared__ int   tok_lds[ROWS][TT];

    const int tid = threadIdx.x, lane = tid & 63, w = tid >> 6;
    const int lo = lane & 15, hi = lane >> 4;
    const int b0 = blockIdx.x * ROWS;
    const int nt0 = (w * NT) >> 3;
    const int cnt = (((w + 1) * NT) >> 3) - nt0;

    s16x8 ikf[4][4], rcf[4][4];
    float bv[4];
#pragma unroll
    for (int i = 0; i < 4; ++i) {
        if (i < cnt) {
            int cp = (nt0 + i) * 16 + lo;
            bv[i] = bias[(cp & 3) * 100 + (cp >> 2)];
#pragma unroll
            for (int ks = 0; ks < 4; ++ks) {
                ikf[i][ks] = *reinterpret_cast<const s16x8*>(ikf_tab  + (((nt0 + i) * 4 + ks) * 64 + lane) * 8);
                rcf[i][ks] = *reinterpret_cast<const s16x8*>(recf_tab + (((nt0 + i) * 4 + ks) * 64 + lane) * 8);
            }
        } else {
            bv[i] = 0.0f;
#pragma unroll
            for (int ks = 0; ks < 4; ++ks) { ikf[i][ks] = (s16x8)0; rcf[i][ks] = (s16x8)0; }
        }
    }
#pragma unroll
    for (int i = 0; i < 4; ++i) {
        asm volatile("" : "+v"(bv[i]));
#pragma unroll
        for (int ks = 0; ks < 4; ++ks) {
            asm volatile("" : "+v"(ikf[i][ks]));
            asm volatile("" : "+v"(rcf[i][ks]));
        }
    }

    for (int idx = tid; idx < 16 * DD; idx += NTHREADS)
        reinterpret_cast<unsigned int*>(&h_lds[0][0])[idx] = 0u;
    for (int idx = tid; idx < ROWS * TT; idx += NTHREADS)
        tok_lds[idx >> 9][idx & (TT - 1)] = tokens[(b0 + (idx >> 9)) * TT + (idx & (TT - 1))];
    if (tid < ROWS * HH) hf_lds[tid] = 0.0f;

    const int  grow = hi;
    const int  gjl  = lo;
    const bool g_on = gjl < 4 * cnt;
    float cst = 0.0f;

    const int xrow = lo & 3;
    int hof[4];
#pragma unroll
    for (int ks = 0; ks < 4; ++ks)
        hof[ks] = (lo * 256 + ks * 64 + hi * 16) ^ ((lo & 7) << 4);

    s16x8 xfA[4], xfB[4];
    {
        int t0 = tokens[(b0 + xrow) * TT + 0];
        int t1 = tokens[(b0 + xrow) * TT + 1];
#pragma unroll
        for (int ks = 0; ks < 4; ++ks) {
            xfA[ks] = *reinterpret_cast<const s16x8*>(emb_bf + (long)t0 * DD + ks * 32 + hi * 8);
            xfB[ks] = *reinterpret_cast<const s16x8*>(emb_bf + (long)t1 * DD + ks * 32 + hi * 8);
        }
    }
    __syncthreads();

    auto step = [&](int t, s16x8 (&xf)[4],
                    const unsigned short* hrd, unsigned short* hwr) {
        s16x8 hA[4];
        if constexpr (ABL == 3 || ABL == 6) {
#pragma unroll
            for (int ks = 0; ks < 4; ++ks) hA[ks] = xf[ks];       // skip LDS read
        } else {
#pragma unroll
            for (int ks = 0; ks < 4; ++ks)
                hA[ks] = *reinterpret_cast<const s16x8*>(reinterpret_cast<const char*>(hrd) + hof[ks]);
        }

        f32x4 acc[4];
#pragma unroll
        for (int i = 0; i < 4; ++i) { acc[i][0] = bv[i]; acc[i][1] = bv[i]; acc[i][2] = bv[i]; acc[i][3] = bv[i]; }

#pragma unroll
        for (int ks = 0; ks < 4; ++ks)
#pragma unroll
            for (int i = 0; i < 4; ++i)
                if (i < cnt) acc[i] = __builtin_amdgcn_mfma_f32_16x16x32_bf16(xf[ks], ikf[i][ks], acc[i], 0, 0, 0);

        if constexpr (ABL != 6 && ABL != 5) {
            int t2 = (t + 2 < TTV) ? t + 2 : TTV - 1;
            int tk = tok_lds[xrow][t2];
            const unsigned short* ep = emb_bf + (long)tk * DD;
#pragma unroll
            for (int ks = 0; ks < 4; ++ks)
                xf[ks] = *reinterpret_cast<const s16x8*>(ep + ks * 32 + hi * 8);
        } else {
#pragma unroll
            for (int ks = 0; ks < 4; ++ks) asm volatile("" : "+v"(xf[ks]));  // keep loop-variant, no load
        }

#pragma unroll
        for (int ks = 0; ks < 4; ++ks)
#pragma unroll
            for (int i = 0; i < 4; ++i)
                if (i < cnt) acc[i] = __builtin_amdgcn_mfma_f32_16x16x32_bf16(hA[ks], rcf[i][ks], acc[i], 0, 0, 0);

        if constexpr (ABL == 6) {
#pragma unroll
            for (int i = 0; i < 4; ++i) asm volatile("" :: "v"(acc[i]));     // keep MFMAs alive
            return;
        } else {
            if (hi == 0) {
#pragma unroll
                for (int i = 0; i < 4; ++i) if (i < cnt)
#pragma unroll
                    for (int r = 0; r < 4; ++r)
                        z_lds[r][(nt0 + i) * 16 + lo] = acc[i][r];
            }
            if (g_on) {
                float4 z4 = *reinterpret_cast<const float4*>(&z_lds[grow][nt0 * 16 + gjl * 4]);
                float ig = sigm(z4.x), fg = sigm(z4.y), gg = tanhx(z4.z), og = sigm(z4.w);
                cst = fg * cst + ig * gg;
                float hh = og * tanhx(cst);
                int j = nt0 * 4 + gjl;
                *reinterpret_cast<unsigned short*>(reinterpret_cast<char*>(hwr) +
                    ((grow * 256 + j * 2) ^ (grow << 4))) = f2b(hh);
                if (t == TTV - 1) hf_lds[grow * HH + j] = hh;
            }
            if constexpr (ABL == 1) {
                asm volatile("" ::: "memory");   // no hardware barrier, no lgkm drain
            } else {
                BARRIER();
            }
        }
    };

    for (int rep = 0; rep < REP; ++rep)
        for (int t = 0; t < TTV; t += 2) {
            step(t,     xfA, h_lds[1], h_lds[0]);
            step(t + 1, xfB, h_lds[0], h_lds[1]);
        }

    asm volatile("" :: "v"(cst));
    if constexpr (ABL == 6) {
        if (tid < ROWS * HH) vout[blockIdx.x * ROWS * HH + tid] = (float)xfA[0][0];
    } else {
        if (tid < ROWS * HH) vout[blockIdx.x * ROWS * HH + tid] = hf_lds[tid];
    }
}

// named wrappers so rocprof rows are unambiguous
#define ABL_ARGS const int* t_, const float* b_, const unsigned short* e_, \
                 const unsigned short* i_, const unsigned short* r_, float* v_
__global__ __launch_bounds__(NTHREADS, 2) void abl0_full_x2_k (ABL_ARGS) { lstm_abl_body<0, TT, 2>(t_, b_, e_, i_, r_, v_); }
__global__ __launch_bounds__(NTHREADS, 2) void abl1_nobar_x4_k(ABL_ARGS) { lstm_abl_body<1, TT, 4>(t_, b_, e_, i_, r_, v_); }
__global__ __launch_bounds__(NTHREADS, 2) void abl3_nohA_x2_k (ABL_ARGS) { lstm_abl_body<3, TT, 2>(t_, b_, e_, i_, r_, v_); }
__global__ __launch_bounds__(NTHREADS, 2) void abl5_nopf_x2_k (ABL_ARGS) { lstm_abl_body<5, TT, 2>(t_, b_, e_, i_, r_, v_); }
__global__ __launch_bounds__(NTHREADS, 2) void abl6_floor_x8_k(ABL_ARGS) { lstm_abl_body<6, TT, 8>(t_, b_, e_, i_, r_, v_); }

extern "C" void kernel_launch(void* const* d_in, const int* in_sizes, int n_in,
                              void* d_out, int out_size, void* d_ws, size_t ws_size,
                              hipStream_t stream) {
    const int*   tokens = (const int*)d_in[0];
    const float* emb    = (const float*)d_in[1];
    const float* kern   = (const float*)d_in[2];
    const float* rec    = (const float*)d_in[3];
    const float* bias   = (const float*)d_in[4];
    const float* dw     = (const float*)d_in[5];
    const float* db     = (const float*)d_in[6];
    float* out = (float*)d_out;

    // ws layout: emb_bf16 (12.8MB) | ikf (100KB) | recf (100KB) | ablation scratch @16MB (5 x 256KB)
    unsigned short* emb_bf = (unsigned short*)d_ws;
    unsigned short* ikf    = emb_bf + (size_t)VOCAB * DD;
    unsigned short* recf   = ikf + NT * 4 * 64 * 8;
    float* vs = (float*)((char*)d_ws + (16u << 20));

    int n4 = VOCAB * DD / 4;
    cast_emb_k<<<(n4 + 255) / 256, 256, 0, stream>>>(emb, emb_bf, n4);
    build_frags_k<<<(2 * NT * 4 * 64 + 255) / 256, 256, 0, stream>>>(kern, rec, ikf, recf);

    // ablation probes — full TT=512 steps, REP-multiplied so each lands in rocprof top-5
    abl0_full_x2_k <<<NBLK, NTHREADS, 0, stream>>>(tokens, bias, emb_bf, ikf, recf, vs + 0 * 65536);
    abl1_nobar_x4_k<<<NBLK, NTHREADS, 0, stream>>>(tokens, bias, emb_bf, ikf, recf, vs + 1 * 65536);
    abl3_nohA_x2_k <<<NBLK, NTHREADS, 0, stream>>>(tokens, bias, emb_bf, ikf, recf, vs + 2 * 65536);
    abl5_nopf_x2_k <<<NBLK, NTHREADS, 0, stream>>>(tokens, bias, emb_bf, ikf, recf, vs + 3 * 65536);
    abl6_floor_x8_k<<<NBLK, NTHREADS, 0, stream>>>(tokens, bias, emb_bf, ikf, recf, vs + 4 * 65536);

    // real kernel (R4 structure, unchanged — produces d_out)
    lstm_fused2_k<<<NBLK, NTHREADS, 0, stream>>>(tokens, bias, dw, db, emb_bf, ikf, recf, out);
}

// Round 10
// 965.062 us; speedup vs baseline: 8.6629x; 8.6629x over previous
//
#include <hip/hip_runtime.h>
#include <hip/hip_bf16.h>

#define VOCAB 50000
#define DD 128
#define TT 512
#define BB 512
#define HH 100
#define NCLS 4
#define NT 25            // 16-wide permuted col tiles covering 4H=400 exactly
#define ROWS 4           // real batch rows per block
#define NBLK (BB/ROWS)   // 128 blocks
#define NTHREADS 512     // 8 waves
#define ZS 400           // z_lds row stride (f32, float4-aligned)

typedef short s16x8 __attribute__((ext_vector_type(8)));
typedef float f32x4 __attribute__((ext_vector_type(4)));

static __device__ __forceinline__ unsigned short f2b(float x) {
    __hip_bfloat16 h = __float2bfloat16(x);
    return __builtin_bit_cast(unsigned short, h);
}
static __device__ __forceinline__ float sigm(float x)  { return __fdividef(1.0f, 1.0f + __expf(-x)); }
static __device__ __forceinline__ float tanhx(float x) { return 1.0f - __fdividef(2.0f, 1.0f + __expf(2.0f * x)); }

#define MFMA(a, b, c) __builtin_amdgcn_mfma_f32_16x16x32_bf16((a), (b), (c), 0, 0, 0)

// raw barrier: waits LDS ops only; global loads (vmcnt) stay in flight
#define BARRIER() asm volatile("s_waitcnt lgkmcnt(0)\n\ts_barrier" ::: "memory")

// ---------------- prep: cast embedding table f32 -> bf16 ----------------
__global__ void cast_emb_k(const float* __restrict__ emb, unsigned short* __restrict__ out, int n4) {
    int i = blockIdx.x * blockDim.x + threadIdx.x;
    if (i < n4) {
        float4 v = reinterpret_cast<const float4*>(emb)[i];
        ushort4 o = make_ushort4(f2b(v.x), f2b(v.y), f2b(v.z), f2b(v.w));
        reinterpret_cast<ushort4*>(out)[i] = o;
    }
}

// ---------------- prep: bake kernel & rec_kernel into per-lane MFMA B-fragments ----------------
// PERMUTED columns: dest col c' = j*4 + gate  <->  orig col = (c'&3)*100 + (c'>>2)
__global__ void build_frags_k(const float* __restrict__ kern, const float* __restrict__ rec,
                              unsigned short* __restrict__ ikf, unsigned short* __restrict__ recf) {
    int tid = blockIdx.x * blockDim.x + threadIdx.x;
    if (tid >= 2 * NT * 4 * 64) return;
    int tab  = tid / (NT * 4 * 64);
    int rem  = tid % (NT * 4 * 64);
    int lane = rem & 63;
    int fs   = rem >> 6;
    int ks   = fs & 3, nt = fs >> 2;
    int cp    = nt * 16 + (lane & 15);           // permuted col
    int oc    = (cp & 3) * 100 + (cp >> 2);      // original col
    int kbase = ks * 32 + (lane >> 4) * 8;
    unsigned short* dst = (tab ? recf : ikf) + rem * 8;
#pragma unroll
    for (int j = 0; j < 8; ++j) {
        int k = kbase + j;
        float v;
        if (tab == 0) v = kern[k * 400 + oc];
        else          v = (k < HH) ? rec[k * 400 + oc] : 0.0f;
        dst[j] = f2b(v);
    }
}

// ---------------- fused LSTM: flattened MFMA tree (depth 2), x-part one step ahead ----------------
__global__ __launch_bounds__(NTHREADS, 2)
void lstm_fused4_k(const int* __restrict__ tokens,
                   const float* __restrict__ bias,
                   const float* __restrict__ dw,
                   const float* __restrict__ db,
                   const unsigned short* __restrict__ emb_bf,
                   const unsigned short* __restrict__ ikf_tab,
                   const unsigned short* __restrict__ recf_tab,
                   float* __restrict__ out)
{
    __shared__ __align__(16) unsigned short h_lds[2][16 * DD];
    __shared__ float z_lds[ROWS][ZS];
    __shared__ float hf_lds[ROWS * HH];
    __shared__ float dw_lds[HH * NCLS];
    __shared__ int   tok_lds[ROWS][TT];

    const int tid = threadIdx.x, lane = tid & 63, w = tid >> 6;
    const int lo = lane & 15, hi = lane >> 4;
    const int b0 = blockIdx.x * ROWS;
    const int nt0 = (w * NT) >> 3;
    const int cnt = (((w + 1) * NT) >> 3) - nt0;   // 3 or 4 tiles per wave

    const f32x4 zero4 = {0.f, 0.f, 0.f, 0.f};

    // weight fragments (held in AGPRs by the compiler) + bias seed vectors per tile
    s16x8 ikf[4][4], rcf[4][4];
    f32x4 bq[4];
#pragma unroll
    for (int i = 0; i < 4; ++i) {
        if (i < cnt) {
            int cp = (nt0 + i) * 16 + lo;
            float bs = bias[(cp & 3) * 100 + (cp >> 2)];
            bq[i][0] = bs; bq[i][1] = bs; bq[i][2] = bs; bq[i][3] = bs;
#pragma unroll
            for (int ks = 0; ks < 4; ++ks) {
                ikf[i][ks] = *reinterpret_cast<const s16x8*>(ikf_tab  + (((nt0 + i) * 4 + ks) * 64 + lane) * 8);
                rcf[i][ks] = *reinterpret_cast<const s16x8*>(recf_tab + (((nt0 + i) * 4 + ks) * 64 + lane) * 8);
            }
        } else {
            bq[i] = zero4;
#pragma unroll
            for (int ks = 0; ks < 4; ++ks) { ikf[i][ks] = (s16x8)0; rcf[i][ks] = (s16x8)0; }
        }
    }
#pragma unroll
    for (int i = 0; i < 4; ++i) {
        asm volatile("" : "+v"(bq[i]));
#pragma unroll
        for (int ks = 0; ks < 4; ++ks) {
            asm volatile("" : "+v"(ikf[i][ks]));
            asm volatile("" : "+v"(rcf[i][ks]));
        }
    }

    for (int idx = tid; idx < 16 * DD; idx += NTHREADS)
        reinterpret_cast<unsigned int*>(&h_lds[0][0])[idx] = 0u;
    for (int idx = tid; idx < ROWS * TT; idx += NTHREADS)
        tok_lds[idx >> 9][idx & (TT - 1)] = tokens[(b0 + (idx >> 9)) * TT + (idx & (TT - 1))];
    if (tid < HH * NCLS) dw_lds[tid] = dw[tid];

    const int  grow = hi;
    const int  gjl  = lo;
    const bool g_on = gjl < 4 * cnt;
    float cst = 0.0f;

    const int xrow = lo & 3;
    int hof[4];
#pragma unroll
    for (int ks = 0; ks < 4; ++ks)
        hof[ks] = (lo * 256 + ks * 64 + hi * 16) ^ ((lo & 7) << 4);

    // x half-accumulators for the CURRENT step: axa = x:ks01 (+0), axb = x:ks23 + bias
    f32x4 axa[4], axb[4];
    // xf double buffer: step t consumes xf[t&1] (holds x(t+1)), then reloads it with x(t+3)
    s16x8 xfA[4], xfB[4];
    {
        // prologue: axa/axb for step 0 from x(0); then preload x(1), x(2)
        int tk0 = tokens[(b0 + xrow) * TT + 0];
        s16x8 x0[4];
#pragma unroll
        for (int ks = 0; ks < 4; ++ks)
            x0[ks] = *reinterpret_cast<const s16x8*>(emb_bf + (long)tk0 * DD + ks * 32 + hi * 8);
#pragma unroll
        for (int i = 0; i < 4; ++i) {
            axa[i] = MFMA(x0[0], ikf[i][0], zero4);
            axb[i] = MFMA(x0[2], ikf[i][2], bq[i]);
        }
#pragma unroll
        for (int i = 0; i < 4; ++i) {
            axa[i] = MFMA(x0[1], ikf[i][1], axa[i]);
            axb[i] = MFMA(x0[3], ikf[i][3], axb[i]);
        }
        int tk1 = tokens[(b0 + xrow) * TT + 1];
        int tk2 = tokens[(b0 + xrow) * TT + 2];
#pragma unroll
        for (int ks = 0; ks < 4; ++ks) {
            xfA[ks] = *reinterpret_cast<const s16x8*>(emb_bf + (long)tk1 * DD + ks * 32 + hi * 8);
            xfB[ks] = *reinterpret_cast<const s16x8*>(emb_bf + (long)tk2 * DD + ks * 32 + hi * 8);
        }
    }
    __syncthreads();

    auto step = [&](int t, s16x8 (&xf)[4],
                    const unsigned short* hrd, unsigned short* hwr) {
        // h fragments (written by all waves last step)
        s16x8 hA[4];
#pragma unroll
        for (int ks = 0; ks < 4; ++ks)
            hA[ks] = *reinterpret_cast<const s16x8*>(reinterpret_cast<const char*>(hrd) + hof[ks]);

        // h level 0: 8 independent MFMAs, seeded with the x half-accumulators
        f32x4 ra[4], rb[4];
#pragma unroll
        for (int i = 0; i < 4; ++i) if (i < cnt) ra[i] = MFMA(hA[0], rcf[i][0], axa[i]);
#pragma unroll
        for (int i = 0; i < 4; ++i) if (i < cnt) rb[i] = MFMA(hA[2], rcf[i][2], axb[i]);

        // x level 0 for t+1 (xf holds x(t+1), loaded 2 steps ago): 8 independent MFMAs
#pragma unroll
        for (int i = 0; i < 4; ++i) if (i < cnt) axa[i] = MFMA(xf[0], ikf[i][0], zero4);
#pragma unroll
        for (int i = 0; i < 4; ++i) if (i < cnt) axb[i] = MFMA(xf[2], ikf[i][2], bq[i]);

        // h level 1 (deps from level 0 are ~16 issues old)
#pragma unroll
        for (int i = 0; i < 4; ++i) if (i < cnt) ra[i] = MFMA(hA[1], rcf[i][1], ra[i]);
#pragma unroll
        for (int i = 0; i < 4; ++i) if (i < cnt) rb[i] = MFMA(hA[3], rcf[i][3], rb[i]);

        // x level 1 (last read of xf this step)
#pragma unroll
        for (int i = 0; i < 4; ++i) if (i < cnt) axa[i] = MFMA(xf[1], ikf[i][1], axa[i]);
#pragma unroll
        for (int i = 0; i < 4; ++i) if (i < cnt) axb[i] = MFMA(xf[3], ikf[i][3], axb[i]);

        // NOW overwrite xf with x(t+3) — after the final read (register renaming
        // still lets the loads issue early; WAR is resolved by the allocator)
        {
            int t3 = (t + 3 < TT) ? t + 3 : TT - 1;
            int tk = tok_lds[xrow][t3];
            const unsigned short* ep = emb_bf + (long)tk * DD;
#pragma unroll
            for (int ks = 0; ks < 4; ++ks)
                xf[ks] = *reinterpret_cast<const s16x8*>(ep + ks * 32 + hi * 8);
        }

        // join: z = ra + rb, write real rows (hi==0) to z_lds (wave-private cols)
        if (hi == 0) {
#pragma unroll
            for (int i = 0; i < 4; ++i) if (i < cnt) {
                f32x4 zv = ra[i] + rb[i];
#pragma unroll
                for (int r = 0; r < 4; ++r)
                    z_lds[r][(nt0 + i) * 16 + lo] = zv[r];
            }
        }

        // gates: read own wave's z (float4 = i,f,g,o thanks to permutation)
        if (g_on) {
            float4 z4 = *reinterpret_cast<const float4*>(&z_lds[grow][nt0 * 16 + gjl * 4]);
            float ig = sigm(z4.x), fg = sigm(z4.y), gg = tanhx(z4.z), og = sigm(z4.w);
            cst = fg * cst + ig * gg;
            float hh = og * tanhx(cst);
            int j = nt0 * 4 + gjl;
            *reinterpret_cast<unsigned short*>(reinterpret_cast<char*>(hwr) +
                ((grow * 256 + j * 2) ^ (grow << 4))) = f2b(hh);
            if (t == TT - 1) hf_lds[grow * HH + j] = hh;
        }
        BARRIER();
    };

    for (int t = 0; t < TT; t += 2) {
        step(t,     xfA, h_lds[1], h_lds[0]);   // read h_{t-1} from buf1, write h_t to buf0
        step(t + 1, xfB, h_lds[0], h_lds[1]);   // read buf0, write buf1
    }

    // epilogue: logits + softmax for this block's 4 rows
    if (tid < ROWS * NCLS) {
        int r = tid >> 2, c = tid & 3;
        float s = db[c];
#pragma unroll 4
        for (int k = 0; k < HH; ++k)
            s += hf_lds[r * HH + k] * dw_lds[k * NCLS + c];
        float mx = s;
        mx = fmaxf(mx, __shfl_xor(mx, 1));
        mx = fmaxf(mx, __shfl_xor(mx, 2));
        float e = __expf(s - mx);
        float den = e;
        den += __shfl_xor(den, 1);
        den += __shfl_xor(den, 2);
        out[(b0 + r) * NCLS + c] = e / den;
    }
}

extern "C" void kernel_launch(void* const* d_in, const int* in_sizes, int n_in,
                              void* d_out, int out_size, void* d_ws, size_t ws_size,
                              hipStream_t stream) {
    const int*   tokens = (const int*)d_in[0];
    const float* emb    = (const float*)d_in[1];
    const float* kern   = (const float*)d_in[2];
    const float* rec    = (const float*)d_in[3];
    const float* bias   = (const float*)d_in[4];
    const float* dw     = (const float*)d_in[5];
    const float* db     = (const float*)d_in[6];
    float* out = (float*)d_out;

    // ws layout: emb_bf16 (12.8MB) | ikf (100KB) | recf (100KB)
    unsigned short* emb_bf = (unsigned short*)d_ws;
    unsigned short* ikf    = emb_bf + (size_t)VOCAB * DD;
    unsigned short* recf   = ikf + NT * 4 * 64 * 8;

    int n4 = VOCAB * DD / 4;
    cast_emb_k<<<(n4 + 255) / 256, 256, 0, stream>>>(emb, emb_bf, n4);
    build_frags_k<<<(2 * NT * 4 * 64 + 255) / 256, 256, 0, stream>>>(kern, rec, ikf, recf);
    lstm_fused4_k<<<NBLK, NTHREADS, 0, stream>>>(tokens, bias, dw, db, emb_bf, ikf, recf, out);
}

// Round 11
// 680.482 us; speedup vs baseline: 12.2858x; 1.4182x over previous
//
#include <hip/hip_runtime.h>
#include <hip/hip_bf16.h>

#define VOCAB 50000
#define DD 128
#define TT 512
#define BB 512
#define HH 100
#define NCLS 4
#define NT 25            // 16-wide permuted col tiles covering 4H=400 exactly
#define ROWS 4           // real batch rows per block
#define NBLK (BB/ROWS)   // 128 blocks
#define NTHREADS 512     // 8 waves
#define ZS 400           // z_lds row stride (f32, float4-aligned)

typedef short s16x8 __attribute__((ext_vector_type(8)));
typedef float f32x4 __attribute__((ext_vector_type(4)));

static __device__ __forceinline__ unsigned short f2b(float x) {
    __hip_bfloat16 h = __float2bfloat16(x);
    return __builtin_bit_cast(unsigned short, h);
}
static __device__ __forceinline__ float sigm(float x)  { return __fdividef(1.0f, 1.0f + __expf(-x)); }
static __device__ __forceinline__ float tanhx(float x) { return 1.0f - __fdividef(2.0f, 1.0f + __expf(2.0f * x)); }

#define MFMA(a, b, c) __builtin_amdgcn_mfma_f32_16x16x32_bf16((a), (b), (c), 0, 0, 0)

// raw barrier: waits LDS ops only; global loads (vmcnt) stay in flight
#define BARRIER() asm volatile("s_waitcnt lgkmcnt(0)\n\ts_barrier" ::: "memory")

// ---------------- prep: cast embedding table f32 -> bf16 ----------------
__global__ void cast_emb_k(const float* __restrict__ emb, unsigned short* __restrict__ out, int n4) {
    int i = blockIdx.x * blockDim.x + threadIdx.x;
    if (i < n4) {
        float4 v = reinterpret_cast<const float4*>(emb)[i];
        ushort4 o = make_ushort4(f2b(v.x), f2b(v.y), f2b(v.z), f2b(v.w));
        reinterpret_cast<ushort4*>(out)[i] = o;
    }
}

// ---------------- prep: bake kernel & rec_kernel into per-lane MFMA B-fragments ----------------
// PERMUTED columns: dest col c' = j*4 + gate  <->  orig col = (c'&3)*100 + (c'>>2)
__global__ void build_frags_k(const float* __restrict__ kern, const float* __restrict__ rec,
                              unsigned short* __restrict__ ikf, unsigned short* __restrict__ recf) {
    int tid = blockIdx.x * blockDim.x + threadIdx.x;
    if (tid >= 2 * NT * 4 * 64) return;
    int tab  = tid / (NT * 4 * 64);
    int rem  = tid % (NT * 4 * 64);
    int lane = rem & 63;
    int fs   = rem >> 6;
    int ks   = fs & 3, nt = fs >> 2;
    int cp    = nt * 16 + (lane & 15);           // permuted col
    int oc    = (cp & 3) * 100 + (cp >> 2);      // original col
    int kbase = ks * 32 + (lane >> 4) * 8;
    unsigned short* dst = (tab ? recf : ikf) + rem * 8;
#pragma unroll
    for (int j = 0; j < 8; ++j) {
        int k = kbase + j;
        float v;
        if (tab == 0) v = kern[k * 400 + oc];
        else          v = (k < HH) ? rec[k * 400 + oc] : 0.0f;
        dst[j] = f2b(v);
    }
}

// ---------------- fused LSTM: register-lean flattened h-tree (depth 2) ----------------
__global__ __launch_bounds__(NTHREADS, 2)
void lstm_fused5_k(const int* __restrict__ tokens,
                   const float* __restrict__ bias,
                   const float* __restrict__ dw,
                   const float* __restrict__ db,
                   const unsigned short* __restrict__ emb_bf,
                   const unsigned short* __restrict__ ikf_tab,
                   const unsigned short* __restrict__ recf_tab,
                   float* __restrict__ out)
{
    __shared__ __align__(16) unsigned short h_lds[2][16 * DD];
    __shared__ float z_lds[ROWS][ZS];
    __shared__ float hf_lds[ROWS * HH];
    __shared__ float dw_lds[HH * NCLS];
    __shared__ int   tok_lds[ROWS][TT];

    const int tid = threadIdx.x, lane = tid & 63, w = tid >> 6;
    const int lo = lane & 15, hi = lane >> 4;
    const int b0 = blockIdx.x * ROWS;
    const int nt0 = (w * NT) >> 3;
    const int cnt = (((w + 1) * NT) >> 3) - nt0;   // 3 or 4 tiles per wave

    const f32x4 zero4 = {0.f, 0.f, 0.f, 0.f};

    // weight fragments (AGPR-resident) + scalar bias per tile
    s16x8 ikf[4][4], rcf[4][4];
    float bv[4];
#pragma unroll
    for (int i = 0; i < 4; ++i) {
        if (i < cnt) {
            int cp = (nt0 + i) * 16 + lo;
            bv[i] = bias[(cp & 3) * 100 + (cp >> 2)];
#pragma unroll
            for (int ks = 0; ks < 4; ++ks) {
                ikf[i][ks] = *reinterpret_cast<const s16x8*>(ikf_tab  + (((nt0 + i) * 4 + ks) * 64 + lane) * 8);
                rcf[i][ks] = *reinterpret_cast<const s16x8*>(recf_tab + (((nt0 + i) * 4 + ks) * 64 + lane) * 8);
            }
        } else {
            bv[i] = 0.0f;
#pragma unroll
            for (int ks = 0; ks < 4; ++ks) { ikf[i][ks] = (s16x8)0; rcf[i][ks] = (s16x8)0; }
        }
    }
#pragma unroll
    for (int i = 0; i < 4; ++i) {
        asm volatile("" : "+v"(bv[i]));
#pragma unroll
        for (int ks = 0; ks < 4; ++ks) {
            asm volatile("" : "+v"(ikf[i][ks]));
            asm volatile("" : "+v"(rcf[i][ks]));
        }
    }

    for (int idx = tid; idx < 16 * DD; idx += NTHREADS)
        reinterpret_cast<unsigned int*>(&h_lds[0][0])[idx] = 0u;
    for (int idx = tid; idx < ROWS * TT; idx += NTHREADS)
        tok_lds[idx >> 9][idx & (TT - 1)] = tokens[(b0 + (idx >> 9)) * TT + (idx & (TT - 1))];
    if (tid < HH * NCLS) dw_lds[tid] = dw[tid];

    const int  grow = hi;
    const int  gjl  = lo;
    const bool g_on = gjl < 4 * cnt;
    float cst = 0.0f;

    const int xrow = lo & 3;
    int hof[4];
#pragma unroll
    for (int ks = 0; ks < 4; ++ks)
        hof[ks] = (lo * 256 + ks * 64 + hi * 16) ^ ((lo & 7) << 4);

    // ax = bias + x(t)@W, computed one step ahead (depth-4 chain, off critical path)
    f32x4 ax[4];
    // xf double buffer: step t consumes xf[t&1] (holds x(t+1)), then reloads with x(t+3)
    s16x8 xfA[4], xfB[4];
    {
        int tk0 = tokens[(b0 + xrow) * TT + 0];
        s16x8 x0[4];
#pragma unroll
        for (int ks = 0; ks < 4; ++ks)
            x0[ks] = *reinterpret_cast<const s16x8*>(emb_bf + (long)tk0 * DD + ks * 32 + hi * 8);
#pragma unroll
        for (int i = 0; i < 4; ++i) {
            f32x4 seed; seed[0] = bv[i]; seed[1] = bv[i]; seed[2] = bv[i]; seed[3] = bv[i];
            ax[i] = MFMA(x0[0], ikf[i][0], seed);
        }
#pragma unroll
        for (int ks = 1; ks < 4; ++ks)
#pragma unroll
            for (int i = 0; i < 4; ++i)
                ax[i] = MFMA(x0[ks], ikf[i][ks], ax[i]);
        int tk1 = tokens[(b0 + xrow) * TT + 1];
        int tk2 = tokens[(b0 + xrow) * TT + 2];
#pragma unroll
        for (int ks = 0; ks < 4; ++ks) {
            xfA[ks] = *reinterpret_cast<const s16x8*>(emb_bf + (long)tk1 * DD + ks * 32 + hi * 8);
            xfB[ks] = *reinterpret_cast<const s16x8*>(emb_bf + (long)tk2 * DD + ks * 32 + hi * 8);
        }
    }
    __syncthreads();

    auto step = [&](int t, s16x8 (&xf)[4],
                    const unsigned short* hrd, unsigned short* hwr) {
        // h fragments (written by all waves last step)
        s16x8 hA[4];
#pragma unroll
        for (int ks = 0; ks < 4; ++ks)
            hA[ks] = *reinterpret_cast<const s16x8*>(reinterpret_cast<const char*>(hrd) + hof[ks]);

        // h-part, two depth-2 chains: ra seeded with ax (bias+x already in), rb seeded 0
        f32x4 ra[4], rb[4];
#pragma unroll
        for (int i = 0; i < 4; ++i) if (i < cnt) ra[i] = MFMA(hA[0], rcf[i][0], ax[i]);
#pragma unroll
        for (int i = 0; i < 4; ++i) if (i < cnt) rb[i] = MFMA(hA[2], rcf[i][2], zero4);
#pragma unroll
        for (int i = 0; i < 4; ++i) if (i < cnt) ra[i] = MFMA(hA[1], rcf[i][1], ra[i]);
#pragma unroll
        for (int i = 0; i < 4; ++i) if (i < cnt) rb[i] = MFMA(hA[3], rcf[i][3], rb[i]);

        // join + z write (real rows only; wave-private col range -> no barrier)
        if (hi == 0) {
#pragma unroll
            for (int i = 0; i < 4; ++i) if (i < cnt) {
                f32x4 zv = ra[i] + rb[i];
#pragma unroll
                for (int r = 0; r < 4; ++r)
                    z_lds[r][(nt0 + i) * 16 + lo] = zv[r];
            }
        }

        // x-part for t+1 (xf holds x(t+1)): depth-4 chain into ax, off critical path.
        // Issued here so it runs under the gate lanes' z-read latency.
#pragma unroll
        for (int i = 0; i < 4; ++i) if (i < cnt) {
            f32x4 seed; seed[0] = bv[i]; seed[1] = bv[i]; seed[2] = bv[i]; seed[3] = bv[i];
            ax[i] = MFMA(xf[0], ikf[i][0], seed);
        }
#pragma unroll
        for (int ks = 1; ks < 4; ++ks)
#pragma unroll
            for (int i = 0; i < 4; ++i)
                if (i < cnt) ax[i] = MFMA(xf[ks], ikf[i][ks], ax[i]);

        // overwrite xf with x(t+3) — strictly after the final read above
        {
            int t3 = (t + 3 < TT) ? t + 3 : TT - 1;
            int tk = tok_lds[xrow][t3];
            const unsigned short* ep = emb_bf + (long)tk * DD;
#pragma unroll
            for (int ks = 0; ks < 4; ++ks)
                xf[ks] = *reinterpret_cast<const s16x8*>(ep + ks * 32 + hi * 8);
        }

        // gates: read own wave's z (float4 = i,f,g,o thanks to permutation)
        if (g_on) {
            float4 z4 = *reinterpret_cast<const float4*>(&z_lds[grow][nt0 * 16 + gjl * 4]);
            float ig = sigm(z4.x), fg = sigm(z4.y), gg = tanhx(z4.z), og = sigm(z4.w);
            cst = fg * cst + ig * gg;
            float hh = og * tanhx(cst);
            int j = nt0 * 4 + gjl;
            *reinterpret_cast<unsigned short*>(reinterpret_cast<char*>(hwr) +
                ((grow * 256 + j * 2) ^ (grow << 4))) = f2b(hh);
            if (t == TT - 1) hf_lds[grow * HH + j] = hh;
        }
        BARRIER();
    };

    for (int t = 0; t < TT; t += 2) {
        step(t,     xfA, h_lds[1], h_lds[0]);   // read h_{t-1} from buf1, write h_t to buf0
        step(t + 1, xfB, h_lds[0], h_lds[1]);   // read buf0, write buf1
    }

    // epilogue: logits + softmax for this block's 4 rows
    if (tid < ROWS * NCLS) {
        int r = tid >> 2, c = tid & 3;
        float s = db[c];
#pragma unroll 4
        for (int k = 0; k < HH; ++k)
            s += hf_lds[r * HH + k] * dw_lds[k * NCLS + c];
        float mx = s;
        mx = fmaxf(mx, __shfl_xor(mx, 1));
        mx = fmaxf(mx, __shfl_xor(mx, 2));
        float e = __expf(s - mx);
        float den = e;
        den += __shfl_xor(den, 1);
        den += __shfl_xor(den, 2);
        out[(b0 + r) * NCLS + c] = e / den;
    }
}

extern "C" void kernel_launch(void* const* d_in, const int* in_sizes, int n_in,
                              void* d_out, int out_size, void* d_ws, size_t ws_size,
                              hipStream_t stream) {
    const int*   tokens = (const int*)d_in[0];
    const float* emb    = (const float*)d_in[1];
    const float* kern   = (const float*)d_in[2];
    const float* rec    = (const float*)d_in[3];
    const float* bias   = (const float*)d_in[4];
    const float* dw     = (const float*)d_in[5];
    const float* db     = (const float*)d_in[6];
    float* out = (float*)d_out;

    // ws layout: emb_bf16 (12.8MB) | ikf (100KB) | recf (100KB)
    unsigned short* emb_bf = (unsigned short*)d_ws;
    unsigned short* ikf    = emb_bf + (size_t)VOCAB * DD;
    unsigned short* recf   = ikf + NT * 4 * 64 * 8;

    int n4 = VOCAB * DD / 4;
    cast_emb_k<<<(n4 + 255) / 256, 256, 0, stream>>>(emb, emb_bf, n4);
    build_frags_k<<<(2 * NT * 4 * 64 + 255) / 256, 256, 0, stream>>>(kern, rec, ikf, recf);
    lstm_fused5_k<<<NBLK, NTHREADS, 0, stream>>>(tokens, bias, dw, db, emb_bf, ikf, recf, out);
}